// Round 1
// 498.856 us; speedup vs baseline: 1.3296x; 1.3296x over previous
//
#include <hip/hip_runtime.h>
#include <hip/hip_bf16.h>
#include <math.h>

#define B_SZ 8
#define L_SZ 1024
#define S_SZ 1000
#define DM   1024      // d_model = H*E = q/k/v row stride
#define DL   4096      // d_llm
#define NH   16
#define EH   64
#define QK_SCALE 0.180336880f   // (1/sqrt(64)) * log2(e): folded into Q projection

typedef __bf16 bf16x8 __attribute__((ext_vector_type(8)));
typedef __bf16 bf16x4 __attribute__((ext_vector_type(4)));
typedef float  f32x4  __attribute__((ext_vector_type(4)));

// async 16-byte global -> LDS (DMA, no VGPR round trip)
__device__ __forceinline__ void async16(const void* g, void* l) {
    __builtin_amdgcn_global_load_lds(
        (const __attribute__((address_space(1))) void*)g,
        (__attribute__((address_space(3))) void*)l, 16, 0, 0);
}

// ---------------------------------------------------------------------------
// fused cast fp32 -> bf16 for target / source / value (exact block counts)
// target n4 = 2097152 (8192 blk), source n4 = 1024000 (4000), value same
// ---------------------------------------------------------------------------
__global__ __launch_bounds__(256) void cast_all_kernel(
    const float* __restrict__ target, const float* __restrict__ source,
    const float* __restrict__ value, __bf16* __restrict__ Tb,
    __bf16* __restrict__ Sb, __bf16* __restrict__ Vb)
{
    int bid = blockIdx.x;
    const float* in; __bf16* out; int i;
    if (bid < 8192)       { in = target; out = Tb; i = bid * 256 + threadIdx.x; }
    else if (bid < 12192) { in = source; out = Sb; i = (bid - 8192)  * 256 + threadIdx.x; }
    else                  { in = value;  out = Vb; i = (bid - 12192) * 256 + threadIdx.x; }
    float4 x = ((const float4*)in)[i];
    bf16x4 y;
    y.x = (__bf16)x.x; y.y = (__bf16)x.y;
    y.z = (__bf16)x.z; y.w = (__bf16)x.w;
    ((bf16x4*)out)[i] = y;
}

// ---------------------------------------------------------------------------
// fused weight transpose+cast: Wq(256 blk) Wk(1024) Wv(1024) Wo(1024)
// W (K,N) fp32 -> WT (N,K) bf16. 64x64 tile.
// ---------------------------------------------------------------------------
__global__ __launch_bounds__(256) void transpose_all_kernel(
    const float* __restrict__ Wq, const float* __restrict__ Wk,
    const float* __restrict__ Wv, const float* __restrict__ Wo,
    __bf16* __restrict__ WqT, __bf16* __restrict__ WkT,
    __bf16* __restrict__ WvT, __bf16* __restrict__ WoT)
{
    __shared__ float t[64][68];
    int bid = blockIdx.x;
    const float* W; __bf16* WT; int K, N, bx, by;
    if (bid < 256)       { W = Wq; WT = WqT; K = DM; N = DM; int u = bid;        bx = u & 15; by = u >> 4; }
    else if (bid < 1280) { W = Wk; WT = WkT; K = DL; N = DM; int u = bid - 256;  bx = u & 15; by = u >> 4; }
    else if (bid < 2304) { W = Wv; WT = WvT; K = DL; N = DM; int u = bid - 1280; bx = u & 15; by = u >> 4; }
    else                 { W = Wo; WT = WoT; K = DM; N = DL; int u = bid - 2304; bx = u & 63; by = u >> 6; }
    const int k0 = by * 64, n0 = bx * 64;
    const int tx = threadIdx.x & 15, ty = threadIdx.x >> 4;

#pragma unroll
    for (int tt = 0; tt < 4; ++tt) {
        int r = ty + 16 * tt;
        float4 x = *(const float4*)&W[(size_t)(k0 + r) * N + n0 + 4 * tx];
        *(float4*)&t[r][4 * tx] = x;
    }
    __syncthreads();
#pragma unroll
    for (int tt = 0; tt < 4; ++tt) {
        int n = ty + 16 * tt;
        bf16x4 y;
        y.x = (__bf16)t[4 * tx + 0][n];
        y.y = (__bf16)t[4 * tx + 1][n];
        y.z = (__bf16)t[4 * tx + 2][n];
        y.w = (__bf16)t[4 * tx + 3][n];
        *(bf16x4*)&WT[(size_t)(n0 + n) * K + k0 + 4 * tx] = y;
    }
}

// ---------------------------------------------------------------------------
// V (S x DM) bf16 -> VT (DM x 1024) bf16, zero-padded for s in [S, 1024).
// ---------------------------------------------------------------------------
__global__ __launch_bounds__(256) void transpose_v_kernel(
    const __bf16* __restrict__ vb, __bf16* __restrict__ vtb)
{
    __shared__ __bf16 t[64][72];
    const int d0 = blockIdx.x * 64, s0 = blockIdx.y * 64;
    const int tid = threadIdx.x;
#pragma unroll
    for (int tt = 0; tt < 2; ++tt) {
        int idx = tt * 256 + tid;
        int r = idx >> 3, ch = idx & 7;
        bf16x8 val;
        if (s0 + r < S_SZ) {
            val = *(const bf16x8*)&vb[(size_t)(s0 + r) * DM + d0 + ch * 8];
        } else {
#pragma unroll
            for (int j = 0; j < 8; ++j) val[j] = (__bf16)0.f;
        }
        *(bf16x8*)&t[r][ch * 8] = val;
    }
    __syncthreads();
#pragma unroll
    for (int tt = 0; tt < 2; ++tt) {
        int idx = tt * 256 + tid;
        int r = idx >> 3, ch = idx & 7;
        bf16x8 o;
#pragma unroll
        for (int j = 0; j < 8; ++j) o[j] = t[ch * 8 + j][r];
        *(bf16x8*)&vtb[(size_t)(d0 + r) * 1024 + s0 + ch * 8] = o;
    }
}

// ---------------------------------------------------------------------------
// m97-style bf16 MFMA GEMM body: C[M,N] = (A[M,K] @ BT[N,K]^T + bias)*oscale
// 128x128 tile, BK=32, 256 thr = 4 waves (2x2), 4x4 MFMA tiles/wave.
// ---------------------------------------------------------------------------
template <bool OUT_BF16>
__device__ __forceinline__ void gemm_body(
    const __bf16* __restrict__ A, const __bf16* __restrict__ BT,
    const float* __restrict__ bias, void* __restrict__ Cv,
    int M, int N, int K, int bx, int by, float oscale,
    __bf16* As, __bf16* Bs)
{
    const int tid  = threadIdx.x;
    const int lane = tid & 63;
    const int wave = tid >> 6;
    const int wr   = wave >> 1;
    const int wc   = wave & 1;
    const int m0   = by * 128;
    const int n0   = bx * 128;
    const int lm   = lane & 15;
    const int lq   = lane >> 4;

    f32x4 acc[4][4];
#pragma unroll
    for (int i = 0; i < 4; ++i)
#pragma unroll
        for (int j = 0; j < 4; ++j)
            acc[i][j] = (f32x4){0.f, 0.f, 0.f, 0.f};

    for (int k0 = 0; k0 < K; k0 += 32) {
#pragma unroll
        for (int t = 0; t < 2; ++t) {
            int chunk = t * 256 + tid;
            int r     = chunk >> 2;
            int koff  = (chunk & 3) * 8;
            int gm = m0 + r; if (gm >= M) gm = M - 1;
            async16(A  + (size_t)gm * K + k0 + koff, (char*)As + chunk * 16);
            int gn = n0 + r;
            async16(BT + (size_t)gn * K + k0 + koff, (char*)Bs + chunk * 16);
        }
        __syncthreads();

        bf16x8 af[4], bf_[4];
#pragma unroll
        for (int i = 0; i < 4; ++i) {
            af[i]  = *(const bf16x8*)&As[(wr * 64 + i * 16 + lm) * 32 + lq * 8];
            bf_[i] = *(const bf16x8*)&Bs[(wc * 64 + i * 16 + lm) * 32 + lq * 8];
        }
#pragma unroll
        for (int i = 0; i < 4; ++i)
#pragma unroll
            for (int j = 0; j < 4; ++j)
                acc[i][j] = __builtin_amdgcn_mfma_f32_16x16x32_bf16(
                    af[i], bf_[j], acc[i][j], 0, 0, 0);
        __syncthreads();
    }

#pragma unroll
    for (int i = 0; i < 4; ++i) {
        int gm0 = m0 + wr * 64 + i * 16 + lq * 4;
#pragma unroll
        for (int j = 0; j < 4; ++j) {
            int gn = n0 + wc * 64 + j * 16 + lm;
            float bv = bias[gn];
#pragma unroll
            for (int r = 0; r < 4; ++r) {
                int gm = gm0 + r;
                if (gm < M) {
                    float val = (acc[i][j][r] + bv) * oscale;
                    if (OUT_BF16)
                        ((__bf16*)Cv)[(size_t)gm * N + gn] = (__bf16)val;
                    else
                        ((float*)Cv)[(size_t)gm * N + gn] = val;
                }
            }
        }
    }
}

template <bool OUT_BF16>
__global__ __launch_bounds__(256) void gemm_bt_kernel(
    const __bf16* __restrict__ A, const __bf16* __restrict__ BT,
    const float* __restrict__ bias, void* __restrict__ Cv,
    int M, int N, int K, float oscale)
{
    __shared__ __bf16 As[128 * 32];
    __shared__ __bf16 Bs[128 * 32];
    gemm_body<OUT_BF16>(A, BT, bias, Cv, M, N, K,
                        blockIdx.x, blockIdx.y, oscale, As, Bs);
}

// ---------------------------------------------------------------------------
// fused Q/K/V projection. 1D grid 640 blocks; long (K=4096) blocks FIRST so
// they start immediately, Q blocks backfill remaining CUs.
//  bid [0,64):    K proj  Sb @ WkT -> kb   (M=1000, K=4096)
//  bid [64,128):  V proj  Vb @ WvT -> vb   (M=1000, K=4096)
//  bid [128,640): Q proj  Tb @ WqT -> qb   (M=8192, K=1024), pre-scaled by
//                 QK_SCALE so attention scores come out in log2 domain.
// ---------------------------------------------------------------------------
__global__ __launch_bounds__(256) void qkv_fused_kernel(
    const __bf16* __restrict__ Tb, const __bf16* __restrict__ Sb,
    const __bf16* __restrict__ Vb,
    const __bf16* __restrict__ WqT, const __bf16* __restrict__ WkT,
    const __bf16* __restrict__ WvT,
    const float* __restrict__ bq, const float* __restrict__ bk,
    const float* __restrict__ bv,
    __bf16* __restrict__ qb, __bf16* __restrict__ kb, __bf16* __restrict__ vb)
{
    __shared__ __bf16 As[128 * 32];
    __shared__ __bf16 Bs[128 * 32];
    int bid = blockIdx.x;
    const __bf16 *A, *BT; const float* bias; __bf16* C;
    int M, K, bx, by; float osc;
    if (bid < 64)       { A = Sb; BT = WkT; bias = bk; C = kb; M = S_SZ; K = DL;
                          bx = bid & 7; by = bid >> 3; osc = 1.f; }
    else if (bid < 128) { int u = bid - 64;  A = Vb; BT = WvT; bias = bv; C = vb;
                          M = S_SZ; K = DL; bx = u & 7; by = u >> 3; osc = 1.f; }
    else                { int u = bid - 128; A = Tb; BT = WqT; bias = bq; C = qb;
                          M = B_SZ * L_SZ; K = DM; bx = u & 7; by = u >> 3; osc = QK_SCALE; }
    gemm_body<true>(A, BT, bias, C, M, DM, K, bx, by, osc, As, Bs);
}

// ---------------------------------------------------------------------------
// MFMA flash attention. Block = 128 Q rows x one (b,h); 4 waves x 32 rows.
// Q pre-scaled by 0.125*log2e -> scores in log2 domain, exp2 direct.
// Double-buffered K/V^T staging, ONE barrier per chunk (prefetch issued at
// top, drained by NEXT chunk's barrier after ~full compute phase).
// Row-sum of P via MFMA-with-ones B operand (no shuffle reduce).
// Defer-max (THR=8 in log2 domain): lane-reduce max + rescale only when a
// row's partial max exceeds running max + 8 (in practice: chunk 0 only).
// LDS: 2*8K (K) + 2*8K (Vt) + 18K (P) = 50 KB -> 3 blocks/CU.
// ---------------------------------------------------------------------------
__global__ __launch_bounds__(256) void attn_mfma_kernel(
    const __bf16* __restrict__ q,   // (B*L, DM), pre-scaled
    const __bf16* __restrict__ k,   // (S, DM)
    const __bf16* __restrict__ vt,  // (DM, 1024) zero-padded s>=S
    __bf16* __restrict__ o)         // (B*L, DM)
{
    __shared__ __bf16 Ks [2][64 * 64];
    __shared__ __bf16 Vts[2][64 * 64];
    __shared__ __bf16 Ps [4][32 * 72];

    const int tid  = threadIdx.x;
    const int lane = tid & 63;
    const int wave = tid >> 6;
    const int lm   = lane & 15;
    const int lq   = lane >> 4;
    const int bh = blockIdx.y;
    const int b  = bh >> 4;
    const int h  = bh & 15;
    const int l0 = blockIdx.x * 128;
    const int row0 = b * L_SZ + l0 + wave * 32;

    // Q fragments (A-layout: m=lm, k=lq*8+j), resident in registers
    bf16x8 qf[2][2];
#pragma unroll
    for (int mt = 0; mt < 2; ++mt)
#pragma unroll
        for (int ks = 0; ks < 2; ++ks)
            qf[mt][ks] = *(const bf16x8*)&q[(size_t)(row0 + mt * 16 + lm) * DM
                                           + h * 64 + ks * 32 + lq * 8];

    f32x4 oa[2][4];
    f32x4 lacc[2];                 // row sums of P (C-layout rows lq*4+r)
    float m_run[2][4];             // running max, log2 domain
#pragma unroll
    for (int mt = 0; mt < 2; ++mt) {
        lacc[mt] = (f32x4){0.f, 0.f, 0.f, 0.f};
#pragma unroll
        for (int r = 0; r < 4; ++r) m_run[mt][r] = -1e30f;
#pragma unroll
        for (int et = 0; et < 4; ++et) oa[mt][et] = (f32x4){0.f, 0.f, 0.f, 0.f};
    }

    bf16x8 vones;
#pragma unroll
    for (int j = 0; j < 8; ++j) vones[j] = (__bf16)1.0f;

    auto stage = [&](int bi, int s0v) {
#pragma unroll
        for (int t = 0; t < 2; ++t) {
            int cc = t * 256 + tid;          // 0..511 16B chunks
            int r = cc >> 3, segL = cc & 7;
            int segG = segL ^ (r & 7);       // source permutation = swizzle
            int sg = s0v + r; if (sg >= S_SZ) sg = S_SZ - 1;
            async16(k  + (size_t)sg * DM + h * 64 + segG * 8,
                    (char*)Ks[bi] + cc * 16);
            async16(vt + (size_t)(h * 64 + r) * 1024 + s0v + segG * 8,
                    (char*)Vts[bi] + cc * 16);
        }
    };

    stage(0, 0);                   // prologue prefetch
    int cur = 0;

    for (int s0 = 0; s0 < S_SZ; s0 += 64) {
        // barrier: (a) drains my vmcnt -> buf[cur] fully staged (issued one
        // full chunk of compute ago); (b) all waves done reading buf[cur^1]
        __syncthreads();
        if (s0 + 64 < S_SZ) stage(cur ^ 1, s0 + 64);   // issue-early prefetch

        // QK^T (scores already in log2 domain via pre-scaled Q)
        f32x4 sc[2][4];
#pragma unroll
        for (int mt = 0; mt < 2; ++mt)
#pragma unroll
            for (int nt = 0; nt < 4; ++nt)
                sc[mt][nt] = (f32x4){0.f, 0.f, 0.f, 0.f};
#pragma unroll
        for (int ks = 0; ks < 2; ++ks)
#pragma unroll
            for (int nt = 0; nt < 4; ++nt) {
                bf16x8 bK = *(const bf16x8*)((const char*)Ks[cur]
                    + (nt * 16 + lm) * 128 + (((ks * 4 + lq) ^ (lm & 7)) * 16));
#pragma unroll
                for (int mt = 0; mt < 2; ++mt)
                    sc[mt][nt] = __builtin_amdgcn_mfma_f32_16x16x32_bf16(
                        qf[mt][ks], bK, sc[mt][nt], 0, 0, 0);
            }

        // S-tail mask: uniform branch, last chunk only
        if (s0 + 64 > S_SZ) {
#pragma unroll
            for (int nt = 0; nt < 4; ++nt) {
                bool masked = (s0 + nt * 16 + lm >= S_SZ);
                if (masked)
#pragma unroll
                    for (int mt = 0; mt < 2; ++mt)
#pragma unroll
                        for (int r = 0; r < 4; ++r) sc[mt][nt][r] = -1e30f;
            }
        }

        // defer-max check: per-thread partial max per row (no lane reduce)
        float pm[2][4];
        bool ok = true;
#pragma unroll
        for (int mt = 0; mt < 2; ++mt)
#pragma unroll
            for (int r = 0; r < 4; ++r) {
                pm[mt][r] = fmaxf(fmaxf(sc[mt][0][r], sc[mt][1][r]),
                                  fmaxf(sc[mt][2][r], sc[mt][3][r]));
                ok = ok && (pm[mt][r] <= m_run[mt][r] + 8.f);
            }
        if (!__all((int)ok)) {
            // rare path (chunk 0): true row max + rescale
#pragma unroll
            for (int mt = 0; mt < 2; ++mt)
#pragma unroll
                for (int r = 0; r < 4; ++r) {
                    float mx = pm[mt][r];
#pragma unroll
                    for (int off = 1; off < 16; off <<= 1)
                        mx = fmaxf(mx, __shfl_xor(mx, off));
                    float mnew  = fmaxf(m_run[mt][r], mx);
                    float alpha = __builtin_amdgcn_exp2f(m_run[mt][r] - mnew);
                    m_run[mt][r] = mnew;
                    lacc[mt][r] *= alpha;
#pragma unroll
                    for (int et = 0; et < 4; ++et)
                        oa[mt][et][r] *= alpha;
                }
        }

        // P = 2^(sc - m), write to wave-private LDS (bounded by 2^8)
#pragma unroll
        for (int mt = 0; mt < 2; ++mt)
#pragma unroll
            for (int r = 0; r < 4; ++r) {
                int prow = (mt * 16 + lq * 4 + r) * 72;
#pragma unroll
                for (int nt = 0; nt < 4; ++nt) {
                    float pv = __builtin_amdgcn_exp2f(sc[mt][nt][r] - m_run[mt][r]);
                    Ps[wave][prow + nt * 16 + lm] = (__bf16)pv;
                }
            }

        // wave-private P round-trip: drain this wave's LDS writes, no barrier
        asm volatile("s_waitcnt lgkmcnt(0)" ::: "memory");

        // PV + row-sum-of-P via MFMA(P, ones): l in same C-layout as oa
#pragma unroll
        for (int ks = 0; ks < 2; ++ks) {
            bf16x8 aP[2];
#pragma unroll
            for (int mt = 0; mt < 2; ++mt)
                aP[mt] = *(const bf16x8*)&Ps[wave][(mt * 16 + lm) * 72
                                                  + ks * 32 + lq * 8];
#pragma unroll
            for (int mt = 0; mt < 2; ++mt)
                lacc[mt] = __builtin_amdgcn_mfma_f32_16x16x32_bf16(
                    aP[mt], vones, lacc[mt], 0, 0, 0);
#pragma unroll
            for (int et = 0; et < 4; ++et) {
                bf16x8 bV = *(const bf16x8*)((const char*)Vts[cur]
                    + (et * 16 + lm) * 128 + (((ks * 4 + lq) ^ (lm & 7)) * 16));
#pragma unroll
                for (int mt = 0; mt < 2; ++mt)
                    oa[mt][et] = __builtin_amdgcn_mfma_f32_16x16x32_bf16(
                        aP[mt], bV, oa[mt][et], 0, 0, 0);
            }
        }
        cur ^= 1;
    }

    // epilogue: normalize, store bf16 (C-layout rows lq*4+r, cols et*16+lm)
#pragma unroll
    for (int mt = 0; mt < 2; ++mt)
#pragma unroll
        for (int r = 0; r < 4; ++r) {
            float inv = 1.f / lacc[mt][r];
            size_t rowi = (size_t)(row0 + mt * 16 + lq * 4 + r) * DM + h * 64;
#pragma unroll
            for (int et = 0; et < 4; ++et)
                o[rowi + et * 16 + lm] = (__bf16)(oa[mt][et][r] * inv);
        }
}

// ---------------------------------------------------------------------------
extern "C" void kernel_launch(void* const* d_in, const int* in_sizes, int n_in,
                              void* d_out, int out_size, void* d_ws, size_t ws_size,
                              hipStream_t stream)
{
    const float* target = (const float*)d_in[0];
    const float* source = (const float*)d_in[1];
    const float* value  = (const float*)d_in[2];
    const float* Wq = (const float*)d_in[3];
    const float* bq = (const float*)d_in[4];
    const float* Wk = (const float*)d_in[5];
    const float* bk = (const float*)d_in[6];
    const float* Wv = (const float*)d_in[7];
    const float* bv = (const float*)d_in[8];
    const float* Wo = (const float*)d_in[9];
    const float* bo = (const float*)d_in[10];
    float* out = (float*)d_out;

    // ws layout (bytes), footprint 64,520,192 (unchanged):
    char* p = (char*)d_ws;
    __bf16* Tb  = (__bf16*)(p);              // target bf16   16,777,216 [ab alias]
    __bf16* Sb  = (__bf16*)(p + 16777216);   // source bf16    8,192,000
    __bf16* vtb = (__bf16*)(p + 16777216);   // V^T bf16 2,097,152 (aliases Sb,
                                             //  written after fused-QKV consumed Sb)
    __bf16* kb  = (__bf16*)(p + 24969216);   // K proj bf16    2,048,000
    __bf16* vb  = (__bf16*)(p + 27017216);   // V proj bf16    2,048,000
    __bf16* WqT = (__bf16*)(p + 29065216);   // Wq^T bf16      2,097,152
    __bf16* WoT = (__bf16*)(p + 31162368);   // Wo^T bf16      8,388,608
    char*   R   =           p + 39550976;    // region 24,969,216
    __bf16* Vb  = (__bf16*)(R);              // value bf16     8,192,000
    __bf16* WvT = (__bf16*)(R + 8192000);    // Wv^T bf16      8,388,608
    __bf16* WkT = (__bf16*)(R + 16580608);   // Wk^T bf16      8,388,608
    // qb lives in d_out (134 MB; scratch is dead before O-proj overwrites it).
    // This removes the qb<->Vb/WvT/WkT alias so Q/K/V projections can run in
    // ONE fused launch.
    __bf16* qb  = (__bf16*)d_out;            // Q proj bf16   16,777,216
    __bf16* ab  = (__bf16*)(p);              // attn out (aliases Tb, dead by then)

    const dim3 blk(256);

    // 1. fused casts (8192 + 4000 + 4000 blocks)
    cast_all_kernel<<<16192, blk, 0, stream>>>(target, source, value, Tb, Sb, Vb);
    // 2. fused weight transposes (256 + 3*1024 blocks)
    transpose_all_kernel<<<3328, blk, 0, stream>>>(Wq, Wk, Wv, Wo, WqT, WkT, WvT, WoT);
    // 3. fused Q/K/V projections (640 blocks, long blocks first)
    qkv_fused_kernel<<<640, blk, 0, stream>>>(Tb, Sb, Vb, WqT, WkT, WvT,
                                              bq, bk, bv, qb, kb, vb);
    // 4. V transpose (after fused launch: vtb aliases Sb, consumed by K proj)
    transpose_v_kernel<<<dim3(16, 16), blk, 0, stream>>>(vb, vtb);
    // 5. MFMA flash attention
    attn_mfma_kernel<<<dim3(8, 128), blk, 0, stream>>>(qb, kb, vtb, ab);
    // 6. output projection (fp32 out, overwrites qb scratch)
    gemm_bt_kernel<false><<<dim3(32, 64), blk, 0, stream>>>(ab, WoT, bo, out,
                                                            B_SZ * L_SZ, DL, DM, 1.0f);
}

// Round 2
// 451.558 us; speedup vs baseline: 1.4689x; 1.1047x over previous
//
#include <hip/hip_runtime.h>
#include <hip/hip_bf16.h>
#include <math.h>

#define B_SZ 8
#define L_SZ 1024
#define S_SZ 1000
#define DM   1024      // d_model = H*E = q/k/v row stride
#define DL   4096      // d_llm
#define NH   16
#define EH   64
#define QK_SCALE 0.180336880f   // (1/sqrt(64)) * log2(e): folded into Q projection

typedef __bf16 bf16x8 __attribute__((ext_vector_type(8)));
typedef __bf16 bf16x4 __attribute__((ext_vector_type(4)));
typedef float  f32x4  __attribute__((ext_vector_type(4)));

// async 16-byte global -> LDS (DMA, no VGPR round trip)
__device__ __forceinline__ void async16(const void* g, void* l) {
    __builtin_amdgcn_global_load_lds(
        (const __attribute__((address_space(1))) void*)g,
        (__attribute__((address_space(3))) void*)l, 16, 0, 0);
}

// ---------------------------------------------------------------------------
// fused cast fp32 -> bf16 for target / source / value
// ---------------------------------------------------------------------------
__global__ __launch_bounds__(256) void cast_all_kernel(
    const float* __restrict__ target, const float* __restrict__ source,
    const float* __restrict__ value, __bf16* __restrict__ Tb,
    __bf16* __restrict__ Sb, __bf16* __restrict__ Vb)
{
    int bid = blockIdx.x;
    const float* in; __bf16* out; int i;
    if (bid < 8192)       { in = target; out = Tb; i = bid * 256 + threadIdx.x; }
    else if (bid < 12192) { in = source; out = Sb; i = (bid - 8192)  * 256 + threadIdx.x; }
    else                  { in = value;  out = Vb; i = (bid - 12192) * 256 + threadIdx.x; }
    float4 x = ((const float4*)in)[i];
    bf16x4 y;
    y.x = (__bf16)x.x; y.y = (__bf16)x.y;
    y.z = (__bf16)x.z; y.w = (__bf16)x.w;
    ((bf16x4*)out)[i] = y;
}

// ---------------------------------------------------------------------------
// fused weight transpose+cast: Wq(256 blk) Wk(1024) Wv(1024) Wo(1024)
// ---------------------------------------------------------------------------
__global__ __launch_bounds__(256) void transpose_all_kernel(
    const float* __restrict__ Wq, const float* __restrict__ Wk,
    const float* __restrict__ Wv, const float* __restrict__ Wo,
    __bf16* __restrict__ WqT, __bf16* __restrict__ WkT,
    __bf16* __restrict__ WvT, __bf16* __restrict__ WoT)
{
    __shared__ float t[64][68];
    int bid = blockIdx.x;
    const float* W; __bf16* WT; int K, N, bx, by;
    if (bid < 256)       { W = Wq; WT = WqT; K = DM; N = DM; int u = bid;        bx = u & 15; by = u >> 4; }
    else if (bid < 1280) { W = Wk; WT = WkT; K = DL; N = DM; int u = bid - 256;  bx = u & 15; by = u >> 4; }
    else if (bid < 2304) { W = Wv; WT = WvT; K = DL; N = DM; int u = bid - 1280; bx = u & 15; by = u >> 4; }
    else                 { W = Wo; WT = WoT; K = DM; N = DL; int u = bid - 2304; bx = u & 63; by = u >> 6; }
    const int k0 = by * 64, n0 = bx * 64;
    const int tx = threadIdx.x & 15, ty = threadIdx.x >> 4;

#pragma unroll
    for (int tt = 0; tt < 4; ++tt) {
        int r = ty + 16 * tt;
        float4 x = *(const float4*)&W[(size_t)(k0 + r) * N + n0 + 4 * tx];
        *(float4*)&t[r][4 * tx] = x;
    }
    __syncthreads();
#pragma unroll
    for (int tt = 0; tt < 4; ++tt) {
        int n = ty + 16 * tt;
        bf16x4 y;
        y.x = (__bf16)t[4 * tx + 0][n];
        y.y = (__bf16)t[4 * tx + 1][n];
        y.z = (__bf16)t[4 * tx + 2][n];
        y.w = (__bf16)t[4 * tx + 3][n];
        *(bf16x4*)&WT[(size_t)(n0 + n) * K + k0 + 4 * tx] = y;
    }
}

// ---------------------------------------------------------------------------
// m97-style bf16 MFMA GEMM body (128x128 tile, BK=32, 4 waves).
// OMODE 0: bf16 out, (acc+bias)*oscale.  OMODE 2: f32 out, raw acc (split-K).
// ---------------------------------------------------------------------------
template <int OMODE>
__device__ __forceinline__ void gemm_body(
    const __bf16* __restrict__ A, int lda,
    const __bf16* __restrict__ BT, int ldb,
    const float* __restrict__ bias, void* __restrict__ Cv,
    int M, int N, int Kext, int bx, int by, float oscale,
    __bf16* As, __bf16* Bs)
{
    const int tid  = threadIdx.x;
    const int lane = tid & 63;
    const int wave = tid >> 6;
    const int wr   = wave >> 1;
    const int wc   = wave & 1;
    const int m0   = by * 128;
    const int n0   = bx * 128;
    const int lm   = lane & 15;
    const int lq   = lane >> 4;

    f32x4 acc[4][4];
#pragma unroll
    for (int i = 0; i < 4; ++i)
#pragma unroll
        for (int j = 0; j < 4; ++j)
            acc[i][j] = (f32x4){0.f, 0.f, 0.f, 0.f};

    for (int k0 = 0; k0 < Kext; k0 += 32) {
#pragma unroll
        for (int t = 0; t < 2; ++t) {
            int chunk = t * 256 + tid;
            int r     = chunk >> 2;
            int koff  = (chunk & 3) * 8;
            int gm = m0 + r; if (gm >= M) gm = M - 1;
            async16(A  + (size_t)gm * lda + k0 + koff, (char*)As + chunk * 16);
            int gn = n0 + r;
            async16(BT + (size_t)gn * ldb + k0 + koff, (char*)Bs + chunk * 16);
        }
        __syncthreads();

        bf16x8 af[4], bf_[4];
#pragma unroll
        for (int i = 0; i < 4; ++i) {
            af[i]  = *(const bf16x8*)&As[(wr * 64 + i * 16 + lm) * 32 + lq * 8];
            bf_[i] = *(const bf16x8*)&Bs[(wc * 64 + i * 16 + lm) * 32 + lq * 8];
        }
#pragma unroll
        for (int i = 0; i < 4; ++i)
#pragma unroll
            for (int j = 0; j < 4; ++j)
                acc[i][j] = __builtin_amdgcn_mfma_f32_16x16x32_bf16(
                    af[i], bf_[j], acc[i][j], 0, 0, 0);
        __syncthreads();
    }

#pragma unroll
    for (int i = 0; i < 4; ++i) {
        int gm0 = m0 + wr * 64 + i * 16 + lq * 4;
#pragma unroll
        for (int j = 0; j < 4; ++j) {
            int gn = n0 + wc * 64 + j * 16 + lm;
            float bv = (OMODE == 0) ? bias[gn] : 0.f;
#pragma unroll
            for (int r = 0; r < 4; ++r) {
                int gm = gm0 + r;
                if (gm < M) {
                    if (OMODE == 0)
                        ((__bf16*)Cv)[(size_t)gm * N + gn] =
                            (__bf16)((acc[i][j][r] + bv) * oscale);
                    else
                        ((float*)Cv)[(size_t)gm * N + gn] = acc[i][j][r];
                }
            }
        }
    }
}

// ---------------------------------------------------------------------------
// fused Q/K/V projection, uniform-work blocks via split-K on K/V:
//  bid [0,256):   K proj partial  ksplit=bid>>6  (M=1000, Kslice=1024) -> kpart
//  bid [256,512): V proj partial                                        -> vpart
//  bid [512,1024): Q proj (M=8192, K=1024), pre-scaled by QK_SCALE      -> qb
// ---------------------------------------------------------------------------
__global__ __launch_bounds__(256) void qkv_fused_kernel(
    const __bf16* __restrict__ Tb, const __bf16* __restrict__ Sb,
    const __bf16* __restrict__ Vb,
    const __bf16* __restrict__ WqT, const __bf16* __restrict__ WkT,
    const __bf16* __restrict__ WvT,
    const float* __restrict__ bq,
    __bf16* __restrict__ qb, float* __restrict__ kpart, float* __restrict__ vpart)
{
    __shared__ __bf16 As[128 * 32];
    __shared__ __bf16 Bs[128 * 32];
    int bid = blockIdx.x;
    if (bid < 512) {
        int proj = bid >> 8;            // 0: K, 1: V
        int u  = bid & 255;
        int ks = u >> 6;                // 0..3 k-split
        int v  = u & 63;
        const __bf16* Aop = (proj ? Vb : Sb) + ks * 1024;
        const __bf16* Bop = (proj ? WvT : WkT) + ks * 1024;
        float* Cp = (proj ? vpart : kpart) + (size_t)ks * 1024000;
        gemm_body<2>(Aop, DL, Bop, DL, nullptr, Cp, S_SZ, DM, 1024,
                     v & 7, v >> 3, 1.f, As, Bs);
    } else {
        int u = bid - 512;
        gemm_body<0>(Tb, DM, WqT, DM, bq, qb, B_SZ * L_SZ, DM, DM,
                     u & 7, u >> 3, QK_SCALE, As, Bs);
    }
}

// ---------------------------------------------------------------------------
// split-K combine:
//  bid [0,1000): kb[s][d] = bf16(sum_j kpart[j] + bk)           (elementwise)
//  bid [1000,1256): vtb[d][s] = bf16(sum_j vpart[j] + bv), transposed 64x64
//                   tile, zero-padded for s >= 1000.
// ---------------------------------------------------------------------------
__global__ __launch_bounds__(256) void combine_kv_kernel(
    const float* __restrict__ kpart, const float* __restrict__ vpart,
    const float* __restrict__ bk, const float* __restrict__ bv,
    __bf16* __restrict__ kb, __bf16* __restrict__ vtb)
{
    __shared__ float t[64][68];
    const int bid = blockIdx.x, tid = threadIdx.x;
    if (bid < 1000) {
        int e4 = bid * 256 + tid;            // float4 index, row = e4>>8
        int col = (e4 & 255) * 4;
        float4 s = *(const float4*)&bk[col];
#pragma unroll
        for (int j = 0; j < 4; ++j) {
            float4 pp = *(const float4*)&kpart[(size_t)j * 1024000 + (size_t)e4 * 4];
            s.x += pp.x; s.y += pp.y; s.z += pp.z; s.w += pp.w;
        }
        bf16x4 y;
        y.x = (__bf16)s.x; y.y = (__bf16)s.y;
        y.z = (__bf16)s.z; y.w = (__bf16)s.w;
        ((bf16x4*)kb)[e4] = y;
    } else {
        int u = bid - 1000;
        int d0 = (u & 15) * 64, s0 = (u >> 4) * 64;
#pragma unroll
        for (int tt = 0; tt < 4; ++tt) {
            int idx = tt * 256 + tid;        // 0..1023
            int r = idx >> 4, c4 = idx & 15;
            float4 s = {0.f, 0.f, 0.f, 0.f};
            if (s0 + r < S_SZ) {
                s = *(const float4*)&bv[d0 + c4 * 4];
#pragma unroll
                for (int j = 0; j < 4; ++j) {
                    float4 pp = *(const float4*)&vpart[(size_t)j * 1024000
                                + (size_t)(s0 + r) * 1024 + d0 + c4 * 4];
                    s.x += pp.x; s.y += pp.y; s.z += pp.z; s.w += pp.w;
                }
            }
            *(float4*)&t[r][c4 * 4] = s;
        }
        __syncthreads();
#pragma unroll
        for (int tt = 0; tt < 2; ++tt) {
            int idx = tt * 256 + tid;        // 0..511
            int d = idx >> 3, ch = idx & 7;
            bf16x8 o;
#pragma unroll
            for (int j = 0; j < 8; ++j) o[j] = (__bf16)t[ch * 8 + j][d];
            *(bf16x8*)&vtb[(size_t)(d0 + d) * 1024 + s0 + ch * 8] = o;
        }
    }
}

// ---------------------------------------------------------------------------
// O-projection: 256x256 tile, BK=32, 512 thr = 8 waves (2M x 4N), TRIPLE-
// buffered LDS (96 KB) with counted vmcnt (T3+T4): compute slot t while
// slot t+1 is landed and t+2 in flight -> boundary wait vmcnt(4), never 0
// in steady state. One raw s_barrier per K-step. XOR-seg swizzle (T2) via
// pre-swizzled global source -> 2-way (free) b128 fragment reads. setprio
// around MFMA clusters (T5). C = A(8192,1024) @ WoT(4096,1024)^T + bo, f32.
// Race-safety: slot t is read only in iter t; its overwrite (tile t+3) is
// issued after boundary-barrier t, behind which all waves drained their own
// tile-t reads (lgkmcnt(0)) -- single barrier suffices with 3 slots.
// ---------------------------------------------------------------------------
__global__ __launch_bounds__(512, 2) void gemm_o8_kernel(
    const __bf16* __restrict__ A, const __bf16* __restrict__ BT,
    const float* __restrict__ bias, float* __restrict__ C)
{
    __shared__ __bf16 sA[3][256 * 32];
    __shared__ __bf16 sB[3][256 * 32];
    const int tid  = threadIdx.x;
    const int lane = tid & 63, wave = tid >> 6;
    const int wr = wave >> 2, wc = wave & 3;       // 2M x 4N waves
    const int lm = lane & 15, lq = lane >> 4;
    const int K = 1024, NT = 32;

    int bid = blockIdx.x;                          // 512 blocks
    bid = (bid & 7) * 64 + (bid >> 3);             // XCD swizzle (512%8==0)
    const int bx = bid & 15, by = bid >> 4;
    const int m0 = by * 256, n0 = bx * 256;

    f32x4 acc[8][4];
#pragma unroll
    for (int i = 0; i < 8; ++i)
#pragma unroll
        for (int j = 0; j < 4; ++j)
            acc[i][j] = (f32x4){0.f, 0.f, 0.f, 0.f};

    auto stage = [&](int slot, int t) {
        const int k0 = t * 32;
#pragma unroll
        for (int i = 0; i < 2; ++i) {
            int cc = i * 512 + tid;                // 16B chunk: row r, seg
            int r  = cc >> 2;
            int sg = (cc & 3) ^ ((r >> 1) & 3);    // pre-swizzled source seg
            async16(A  + (size_t)(m0 + r) * K + k0 + sg * 8,
                    (char*)sA[slot] + cc * 16);
            async16(BT + (size_t)(n0 + r) * K + k0 + sg * 8,
                    (char*)sB[slot] + cc * 16);
        }
    };

    // prologue: slots 0,1 in flight; land slot 0, keep slot 1 outstanding
    stage(0, 0);
    stage(1, 1);
    asm volatile("s_waitcnt vmcnt(4)" ::: "memory");
    __builtin_amdgcn_s_barrier();
    __builtin_amdgcn_sched_barrier(0);

    int sl = 0;
    for (int t = 0; t < NT; ++t) {
        if (t + 2 < NT) {
            int s2 = sl + 2; if (s2 >= 3) s2 -= 3;
            stage(s2, t + 2);                      // issue-early, 4 loads
        }
        // 12 ds_reads from slot sl (landed): group1 = fb0-3 + fa0-3
        bf16x8 fb[4], fa[8];
#pragma unroll
        for (int ni = 0; ni < 4; ++ni) {
            int rr = wc * 64 + ni * 16 + lm;
            fb[ni] = *(const bf16x8*)((const char*)sB[sl]
                     + rr * 64 + ((lq ^ ((rr >> 1) & 3)) * 16));
        }
#pragma unroll
        for (int mi = 0; mi < 4; ++mi) {
            int rr = wr * 128 + mi * 16 + lm;
            fa[mi] = *(const bf16x8*)((const char*)sA[sl]
                     + rr * 64 + ((lq ^ ((rr >> 1) & 3)) * 16));
        }
        __builtin_amdgcn_sched_barrier(0);         // pin group1 before group2
#pragma unroll
        for (int mi = 4; mi < 8; ++mi) {
            int rr = wr * 128 + mi * 16 + lm;
            fa[mi] = *(const bf16x8*)((const char*)sA[sl]
                     + rr * 64 + ((lq ^ ((rr >> 1) & 3)) * 16));
        }
        asm volatile("s_waitcnt lgkmcnt(4)" ::: "memory");  // group1 landed
        __builtin_amdgcn_sched_barrier(0);
        __builtin_amdgcn_s_setprio(1);
#pragma unroll
        for (int mi = 0; mi < 4; ++mi)
#pragma unroll
            for (int ni = 0; ni < 4; ++ni)
                acc[mi][ni] = __builtin_amdgcn_mfma_f32_16x16x32_bf16(
                    fa[mi], fb[ni], acc[mi][ni], 0, 0, 0);
        __builtin_amdgcn_s_setprio(0);
        asm volatile("s_waitcnt lgkmcnt(0)" ::: "memory");  // group2 landed
        __builtin_amdgcn_sched_barrier(0);
        __builtin_amdgcn_s_setprio(1);
#pragma unroll
        for (int mi = 4; mi < 8; ++mi)
#pragma unroll
            for (int ni = 0; ni < 4; ++ni)
                acc[mi][ni] = __builtin_amdgcn_mfma_f32_16x16x32_bf16(
                    fa[mi], fb[ni], acc[mi][ni], 0, 0, 0);
        __builtin_amdgcn_s_setprio(0);
        // boundary: land slot t+1 (keep t+2's 4 loads in flight)
        if (t + 2 < NT)
            asm volatile("s_waitcnt vmcnt(4)" ::: "memory");
        else
            asm volatile("s_waitcnt vmcnt(0)" ::: "memory");
        __builtin_amdgcn_s_barrier();
        __builtin_amdgcn_sched_barrier(0);
        if (++sl == 3) sl = 0;
    }

    // epilogue: f32 + bias, coalesced dword stores
#pragma unroll
    for (int mi = 0; mi < 8; ++mi) {
        int gm0 = m0 + wr * 128 + mi * 16 + lq * 4;
#pragma unroll
        for (int ni = 0; ni < 4; ++ni) {
            int gn = n0 + wc * 64 + ni * 16 + lm;
            float bv = bias[gn];
#pragma unroll
            for (int r = 0; r < 4; ++r)
                C[(size_t)(gm0 + r) * 4096 + gn] = acc[mi][ni][r] + bv;
        }
    }
}

// ---------------------------------------------------------------------------
// MFMA flash attention (unchanged from prev round).
// ---------------------------------------------------------------------------
__global__ __launch_bounds__(256) void attn_mfma_kernel(
    const __bf16* __restrict__ q,   // (B*L, DM), pre-scaled
    const __bf16* __restrict__ k,   // (S, DM)
    const __bf16* __restrict__ vt,  // (DM, 1024) zero-padded s>=S
    __bf16* __restrict__ o)         // (B*L, DM)
{
    __shared__ __bf16 Ks [2][64 * 64];
    __shared__ __bf16 Vts[2][64 * 64];
    __shared__ __bf16 Ps [4][32 * 72];

    const int tid  = threadIdx.x;
    const int lane = tid & 63;
    const int wave = tid >> 6;
    const int lm   = lane & 15;
    const int lq   = lane >> 4;
    const int bh = blockIdx.y;
    const int b  = bh >> 4;
    const int h  = bh & 15;
    const int l0 = blockIdx.x * 128;
    const int row0 = b * L_SZ + l0 + wave * 32;

    bf16x8 qf[2][2];
#pragma unroll
    for (int mt = 0; mt < 2; ++mt)
#pragma unroll
        for (int ks = 0; ks < 2; ++ks)
            qf[mt][ks] = *(const bf16x8*)&q[(size_t)(row0 + mt * 16 + lm) * DM
                                           + h * 64 + ks * 32 + lq * 8];

    f32x4 oa[2][4];
    f32x4 lacc[2];
    float m_run[2][4];
#pragma unroll
    for (int mt = 0; mt < 2; ++mt) {
        lacc[mt] = (f32x4){0.f, 0.f, 0.f, 0.f};
#pragma unroll
        for (int r = 0; r < 4; ++r) m_run[mt][r] = -1e30f;
#pragma unroll
        for (int et = 0; et < 4; ++et) oa[mt][et] = (f32x4){0.f, 0.f, 0.f, 0.f};
    }

    bf16x8 vones;
#pragma unroll
    for (int j = 0; j < 8; ++j) vones[j] = (__bf16)1.0f;

    auto stage = [&](int bi, int s0v) {
#pragma unroll
        for (int t = 0; t < 2; ++t) {
            int cc = t * 256 + tid;
            int r = cc >> 3, segL = cc & 7;
            int segG = segL ^ (r & 7);
            int sg = s0v + r; if (sg >= S_SZ) sg = S_SZ - 1;
            async16(k  + (size_t)sg * DM + h * 64 + segG * 8,
                    (char*)Ks[bi] + cc * 16);
            async16(vt + (size_t)(h * 64 + r) * 1024 + s0v + segG * 8,
                    (char*)Vts[bi] + cc * 16);
        }
    };

    stage(0, 0);
    int cur = 0;

    for (int s0 = 0; s0 < S_SZ; s0 += 64) {
        __syncthreads();
        if (s0 + 64 < S_SZ) stage(cur ^ 1, s0 + 64);

        f32x4 sc[2][4];
#pragma unroll
        for (int mt = 0; mt < 2; ++mt)
#pragma unroll
            for (int nt = 0; nt < 4; ++nt)
                sc[mt][nt] = (f32x4){0.f, 0.f, 0.f, 0.f};
#pragma unroll
        for (int ks = 0; ks < 2; ++ks)
#pragma unroll
            for (int nt = 0; nt < 4; ++nt) {
                bf16x8 bK = *(const bf16x8*)((const char*)Ks[cur]
                    + (nt * 16 + lm) * 128 + (((ks * 4 + lq) ^ (lm & 7)) * 16));
#pragma unroll
                for (int mt = 0; mt < 2; ++mt)
                    sc[mt][nt] = __builtin_amdgcn_mfma_f32_16x16x32_bf16(
                        qf[mt][ks], bK, sc[mt][nt], 0, 0, 0);
            }

        if (s0 + 64 > S_SZ) {
#pragma unroll
            for (int nt = 0; nt < 4; ++nt) {
                bool masked = (s0 + nt * 16 + lm >= S_SZ);
                if (masked)
#pragma unroll
                    for (int mt = 0; mt < 2; ++mt)
#pragma unroll
                        for (int r = 0; r < 4; ++r) sc[mt][nt][r] = -1e30f;
            }
        }

        float pm[2][4];
        bool ok = true;
#pragma unroll
        for (int mt = 0; mt < 2; ++mt)
#pragma unroll
            for (int r = 0; r < 4; ++r) {
                pm[mt][r] = fmaxf(fmaxf(sc[mt][0][r], sc[mt][1][r]),
                                  fmaxf(sc[mt][2][r], sc[mt][3][r]));
                ok = ok && (pm[mt][r] <= m_run[mt][r] + 8.f);
            }
        if (!__all((int)ok)) {
#pragma unroll
            for (int mt = 0; mt < 2; ++mt)
#pragma unroll
                for (int r = 0; r < 4; ++r) {
                    float mx = pm[mt][r];
#pragma unroll
                    for (int off = 1; off < 16; off <<= 1)
                        mx = fmaxf(mx, __shfl_xor(mx, off));
                    float mnew  = fmaxf(m_run[mt][r], mx);
                    float alpha = __builtin_amdgcn_exp2f(m_run[mt][r] - mnew);
                    m_run[mt][r] = mnew;
                    lacc[mt][r] *= alpha;
#pragma unroll
                    for (int et = 0; et < 4; ++et)
                        oa[mt][et][r] *= alpha;
                }
        }

#pragma unroll
        for (int mt = 0; mt < 2; ++mt)
#pragma unroll
            for (int r = 0; r < 4; ++r) {
                int prow = (mt * 16 + lq * 4 + r) * 72;
#pragma unroll
                for (int nt = 0; nt < 4; ++nt) {
                    float pv = __builtin_amdgcn_exp2f(sc[mt][nt][r] - m_run[mt][r]);
                    Ps[wave][prow + nt * 16 + lm] = (__bf16)pv;
                }
            }

        asm volatile("s_waitcnt lgkmcnt(0)" ::: "memory");

#pragma unroll
        for (int ks = 0; ks < 2; ++ks) {
            bf16x8 aP[2];
#pragma unroll
            for (int mt = 0; mt < 2; ++mt)
                aP[mt] = *(const bf16x8*)&Ps[wave][(mt * 16 + lm) * 72
                                                  + ks * 32 + lq * 8];
#pragma unroll
            for (int mt = 0; mt < 2; ++mt)
                lacc[mt] = __builtin_amdgcn_mfma_f32_16x16x32_bf16(
                    aP[mt], vones, lacc[mt], 0, 0, 0);
#pragma unroll
            for (int et = 0; et < 4; ++et) {
                bf16x8 bV = *(const bf16x8*)((const char*)Vts[cur]
                    + (et * 16 + lm) * 128 + (((ks * 4 + lq) ^ (lm & 7)) * 16));
#pragma unroll
                for (int mt = 0; mt < 2; ++mt)
                    oa[mt][et] = __builtin_amdgcn_mfma_f32_16x16x32_bf16(
                        aP[mt], bV, oa[mt][et], 0, 0, 0);
            }
        }
        cur ^= 1;
    }

#pragma unroll
    for (int mt = 0; mt < 2; ++mt)
#pragma unroll
        for (int r = 0; r < 4; ++r) {
            float inv = 1.f / lacc[mt][r];
            size_t rowi = (size_t)(row0 + mt * 16 + lq * 4 + r) * DM + h * 64;
#pragma unroll
            for (int et = 0; et < 4; ++et)
                o[rowi + et * 16 + lm] = (__bf16)(oa[mt][et][r] * inv);
        }
}

// ---------------------------------------------------------------------------
extern "C" void kernel_launch(void* const* d_in, const int* in_sizes, int n_in,
                              void* d_out, int out_size, void* d_ws, size_t ws_size,
                              hipStream_t stream)
{
    const float* target = (const float*)d_in[0];
    const float* source = (const float*)d_in[1];
    const float* value  = (const float*)d_in[2];
    const float* Wq = (const float*)d_in[3];
    const float* bq = (const float*)d_in[4];
    const float* Wk = (const float*)d_in[5];
    const float* bk = (const float*)d_in[6];
    const float* Wv = (const float*)d_in[7];
    const float* bv = (const float*)d_in[8];
    const float* Wo = (const float*)d_in[9];
    const float* bo = (const float*)d_in[10];
    float* out = (float*)d_out;

    // ws layout (bytes):
    char* p = (char*)d_ws;
    __bf16* Tb  = (__bf16*)(p);              // target bf16   16,777,216 [ab alias]
    __bf16* Sb  = (__bf16*)(p + 16777216);   // source bf16    8,192,000
    __bf16* vtb = (__bf16*)(p + 16777216);   // V^T bf16 2,097,152 (aliases Sb,
                                             //  written by combine after QKV done)
    __bf16* kb  = (__bf16*)(p + 24969216);   // K proj bf16    2,048,000
    __bf16* WqT = (__bf16*)(p + 29065216);   // Wq^T bf16      2,097,152
    __bf16* WoT = (__bf16*)(p + 31162368);   // Wo^T bf16      8,388,608
    char*   R   =           p + 39550976;    // region 24,969,216
    __bf16* Vb  = (__bf16*)(R);              // value bf16     8,192,000
    __bf16* WvT = (__bf16*)(R + 8192000);    // Wv^T bf16      8,388,608
    __bf16* WkT = (__bf16*)(R + 16580608);   // Wk^T bf16      8,388,608
    // d_out (134 MB) doubles as scratch until the final O-proj overwrites it:
    __bf16* qb    = (__bf16*)d_out;                       // 16,777,216
    float*  kpart = (float*)((char*)d_out + 16777216);    // 4x1000x1024 f32 16,384,000
    float*  vpart = (float*)((char*)d_out + 33161216);    // 16,384,000
    __bf16* ab    = (__bf16*)(p);            // attn out (aliases Tb, dead by then)

    const dim3 blk(256);

    // 1. fused casts
    cast_all_kernel<<<16192, blk, 0, stream>>>(target, source, value, Tb, Sb, Vb);
    // 2. fused weight transposes
    transpose_all_kernel<<<3328, blk, 0, stream>>>(Wq, Wk, Wv, Wo, WqT, WkT, WvT, WoT);
    // 3. fused Q/K/V projections (uniform 34-MFLOP blocks via split-K x4)
    qkv_fused_kernel<<<1024, blk, 0, stream>>>(Tb, Sb, Vb, WqT, WkT, WvT,
                                               bq, qb, kpart, vpart);
    // 4. split-K combine: kb elementwise; vtb transposed+padded
    combine_kv_kernel<<<1256, blk, 0, stream>>>(kpart, vpart, bk, bv, kb, vtb);
    // 5. MFMA flash attention
    attn_mfma_kernel<<<dim3(8, 128), blk, 0, stream>>>(qb, kb, vtb, ab);
    // 6. output projection: 256^2 triple-buffered counted-vmcnt kernel
    gemm_o8_kernel<<<512, 512, 0, stream>>>(ab, WoT, bo, out);
}